// Round 7
// baseline (592.680 us; speedup 1.0000x reference)
//
#include <hip/hip_runtime.h>

// Problem constants (fixed by the reference)
#define NN   50000
#define EE   800000
#define DD   64
#define HH   128
#define KIN  320          // 5 * 64
#define TILE_E 64

typedef __bf16 bf16x8 __attribute__((ext_vector_type(8)));
typedef float  f32x4  __attribute__((ext_vector_type(4)));

#if __has_builtin(__builtin_amdgcn_cvt_pk_bf16_f32)
typedef __bf16 bf16x2_t __attribute__((ext_vector_type(2)));
__device__ __forceinline__ unsigned int pk2(float a, float b) {
  union { bf16x2_t v; unsigned int u; } cv;
  cv.v = __builtin_amdgcn_cvt_pk_bf16_f32(a, b);
  return cv.u;
}
__device__ __forceinline__ unsigned short f2bf(float a) {
  return (unsigned short)(pk2(a, a) & 0xFFFFu);
}
#else
__device__ __forceinline__ unsigned short f2bf(float f) {
  union { float f; unsigned int u; } v; v.f = f;
  unsigned int u = v.u + 0x7FFFu + ((v.u >> 16) & 1u);   // RTNE
  return (unsigned short)(u >> 16);
}
__device__ __forceinline__ unsigned int pk2(float a, float b) {
  return (unsigned int)f2bf(a) | ((unsigned int)f2bf(b) << 16);
}
#endif

__device__ __forceinline__ float bf2f(unsigned short b) {
  union { unsigned int u; float f; } v; v.u = ((unsigned int)b) << 16; return v.f;
}

// Packed, pad-free psi layout in 16B units: unit = (mt*10 + k0)*64 + row15*4 + quad
// u16 index for (row in [0,64), kk in [0,320)):
__device__ __forceinline__ int psiIdx(int row, int kk) {
  return ((((row >> 4) * 10 + (kk >> 5)) << 6) + ((row & 15) << 2) + ((kk >> 3) & 3)) * 8
         + (kk & 7);
}

// ---------------------------------------------------------------------------
// fp32 weights -> bf16, transposed to [n][k] so MFMA B-fragments are 16B runs.
// ---------------------------------------------------------------------------
__global__ __launch_bounds__(256) void prep_weights(
    const float* __restrict__ W0,
    const float* __restrict__ W1,
    const float* __restrict__ W2,
    unsigned short* __restrict__ WT0,
    unsigned short* __restrict__ WT1,
    unsigned short* __restrict__ WT2) {
  int t = blockIdx.x * 256 + threadIdx.x;
  if (t < KIN * HH) {
    int k = t / HH, n = t % HH;
    WT0[n * KIN + k] = f2bf(W0[t]);
  } else if (t < KIN * HH + HH * HH) {
    int u = t - KIN * HH; int k = u / HH, n = u % HH;
    WT1[n * HH + k] = f2bf(W1[u]);
  } else {
    int u = t - KIN * HH - HH * HH; int k = u / DD, n = u % DD;
    WT2[n * HH + k] = f2bf(W2[u]);
  }
}

// ---------------------------------------------------------------------------
// fp32 node tables -> bf16 tables (halves random-gather bytes in edge_mlp).
// ---------------------------------------------------------------------------
__global__ __launch_bounds__(256) void prep_tables(
    const float* __restrict__ hd, const float* __restrict__ hs,
    unsigned short* __restrict__ hdb, unsigned short* __restrict__ hsb) {
  int t = blockIdx.x * 256 + threadIdx.x;
  const int n = NN * DD / 8;              // 400000
  const float* src; unsigned short* dst; int i;
  if (t < n) { src = hd; dst = hdb; i = t; }
  else       { src = hs; dst = hsb; i = t - n; }
  float4 a = *(const float4*)(src + (size_t)i * 8);
  float4 b = *(const float4*)(src + (size_t)i * 8 + 4);
  uint4 w;
  w.x = pk2(a.x, a.y); w.y = pk2(a.z, a.w);
  w.z = pk2(b.x, b.y); w.w = pk2(b.z, b.w);
  *(uint4*)(dst + (size_t)i * 8) = w;
}

// ---------------------------------------------------------------------------
// Fused edge kernel. 512 threads (8 waves), 64 edges/block, LDS = 40960 B
// -> 4 blocks/CU x 8 waves = 32 waves/CU (100% occupancy).
// Wave w owns hidden cols [16w,16w+16) for layers 0/1; for layer 2, wave w
// owns n-tile (w&3) and m-tiles {2*(w>>2), 2*(w>>2)+1}.
// MFMA 16x16x32 bf16. A: m=lane&15, k=quad*8+j. B: n=lane&15, k=quad*8+j.
// C/D: col=lane&15, row=quad*4+reg.
// ---------------------------------------------------------------------------
__global__ __launch_bounds__(512, 8) void edge_mlp(
    const unsigned short* __restrict__ hdb,  // h_d_prev [N][64] bf16
    const unsigned short* __restrict__ hsb,  // h_s      [N][64] bf16
    const float* __restrict__ ef,            // edge_feat[E][64] fp32
    const int* __restrict__ snd,
    const int* __restrict__ rcv,
    const unsigned short* __restrict__ WT0,  // [128][320] bf16
    const float* __restrict__ b0,            // [128]
    const unsigned short* __restrict__ WT1,  // [128][128] bf16
    const float* __restrict__ b1,            // [128]
    const unsigned short* __restrict__ WT2,  // [64][128] bf16
    const float* __restrict__ b2,            // [64]
    float* __restrict__ agg)                 // [N][64] fp32
{
  __shared__ __align__(16) unsigned short psi[TILE_E * KIN];  // 40960 B exactly

  const int tid  = threadIdx.x;
  const int e0   = blockIdx.x * TILE_E;
  const int wv   = tid >> 6;          // 0..7
  const int lane = tid & 63;
  const int ln   = lane & 15;
  const int quad = lane >> 4;
  const int mtb  = (wv >> 2) * 2;     // layer-2 m-tile base (0 or 2)

  // Preload the 8 receiver indices this lane scatters to (hidden by gather).
  int ridx[8];
  #pragma unroll
  for (int t = 0; t < 2; ++t)
    #pragma unroll
    for (int i = 0; i < 4; ++i)
      ridx[t * 4 + i] = rcv[e0 + (mtb + t) * 16 + quad * 4 + i];

  // Gather: 5 segs x 64 edges x 8 chunks = 2560 jobs, 5 per thread.
  // job = seg*512 + tid  ->  e = tid>>3 (same edge for all segs), c = tid&7.
  {
    const int e = tid >> 3;
    const int c = tid & 7;
    #pragma unroll
    for (int seg = 0; seg < 5; ++seg) {
      int unit = (((e >> 4) * 10 + seg * 2 + (c >> 2)) << 6) + ((e & 15) << 2) + (c & 3);
      uint4 w;
      if (seg < 4) {
        const unsigned short* tb = (seg & 2) ? hdb : hsb;   // 0,1=h_s  2,3=h_d
        const int* ix = (seg & 1) ? rcv : snd;
        w = *(const uint4*)(tb + (size_t)ix[e0 + e] * DD + c * 8);
      } else {
        const float* src = ef + (size_t)(e0 + e) * DD;
        float4 v0 = *(const float4*)(src + c * 8);
        float4 v1 = *(const float4*)(src + c * 8 + 4);
        w.x = pk2(v0.x, v0.y); w.y = pk2(v0.z, v0.w);
        w.z = pk2(v1.x, v1.y); w.w = pk2(v1.z, v1.w);
      }
      *(uint4*)(&psi[unit * 8]) = w;
    }
  }
  __syncthreads();

  f32x4 acc[4];

  // ------------------ Layer 0: [64,320] @ [320,128] ------------------------
  {
    #pragma unroll
    for (int m = 0; m < 4; ++m) acc[m] = (f32x4){0,0,0,0};
    const unsigned short* wb = WT0 + (wv * 16 + ln) * KIN + quad * 8;
    #pragma unroll
    for (int k0 = 0; k0 < 10; ++k0) {
      bf16x8 bf = *(const bf16x8*)(wb + k0 * 32);
      #pragma unroll
      for (int mt = 0; mt < 4; ++mt) {
        bf16x8 af = *(const bf16x8*)(&psi[(((mt * 10 + k0) << 6) + (ln << 2) + quad) * 8]);
        acc[mt] = __builtin_amdgcn_mfma_f32_16x16x32_bf16(af, bf, acc[mt], 0, 0, 0);
      }
    }
  }
  __syncthreads();          // psi input reads done -> safe to overwrite kk[0,128)

  // h1 -> kk [0,128): wave w writes cols [16w,16w+16)
  {
    float bv = b0[wv * 16 + ln];
    #pragma unroll
    for (int mt = 0; mt < 4; ++mt) {
      #pragma unroll
      for (int i = 0; i < 4; ++i) {
        int unit = ((mt * 10 + (wv >> 1)) << 6) + ((quad * 4 + i) << 2)
                 + (wv & 1) * 2 + (ln >> 3);
        float v = acc[mt][i] + bv; v = v > 0.f ? v : 0.f;
        psi[unit * 8 + (ln & 7)] = f2bf(v);
      }
    }
  }
  __syncthreads();

  // ------------------ Layer 1: [64,128] @ [128,128] ------------------------
  {
    #pragma unroll
    for (int m = 0; m < 4; ++m) acc[m] = (f32x4){0,0,0,0};
    const unsigned short* wb = WT1 + (wv * 16 + ln) * HH + quad * 8;
    #pragma unroll
    for (int k0 = 0; k0 < 4; ++k0) {
      bf16x8 bf = *(const bf16x8*)(wb + k0 * 32);
      #pragma unroll
      for (int mt = 0; mt < 4; ++mt) {
        bf16x8 af = *(const bf16x8*)(&psi[(((mt * 10 + k0) << 6) + (ln << 2) + quad) * 8]);
        acc[mt] = __builtin_amdgcn_mfma_f32_16x16x32_bf16(af, bf, acc[mt], 0, 0, 0);
      }
    }
  }
  __syncthreads();          // h1 reads done -> overwrite with h2

  {
    float bv = b1[wv * 16 + ln];
    #pragma unroll
    for (int mt = 0; mt < 4; ++mt) {
      #pragma unroll
      for (int i = 0; i < 4; ++i) {
        int unit = ((mt * 10 + (wv >> 1)) << 6) + ((quad * 4 + i) << 2)
                 + (wv & 1) * 2 + (ln >> 3);
        float v = acc[mt][i] + bv; v = v > 0.f ? v : 0.f;
        psi[unit * 8 + (ln & 7)] = f2bf(v);
      }
    }
  }
  __syncthreads();

  // ---------- Layer 2: [64,128] @ [128,64] + s_ij + atomic scatter ---------
  {
    f32x4 a2[2];
    a2[0] = (f32x4){0,0,0,0}; a2[1] = (f32x4){0,0,0,0};
    const unsigned short* wb = WT2 + ((wv & 3) * 16 + ln) * HH + quad * 8;
    #pragma unroll
    for (int k0 = 0; k0 < 4; ++k0) {
      bf16x8 bf = *(const bf16x8*)(wb + k0 * 32);
      #pragma unroll
      for (int t = 0; t < 2; ++t) {
        int mt = mtb + t;
        bf16x8 af = *(const bf16x8*)(&psi[(((mt * 10 + k0) << 6) + (ln << 2) + quad) * 8]);
        a2[t] = __builtin_amdgcn_mfma_f32_16x16x32_bf16(af, bf, a2[t], 0, 0, 0);
      }
    }
    int   col = (wv & 3) * 16 + ln;
    float bv  = b2[col];
    #pragma unroll
    for (int t = 0; t < 2; ++t) {
      #pragma unroll
      for (int i = 0; i < 4; ++i) {
        int row = (mtb + t) * 16 + quad * 4 + i;
        float p  = a2[t][i] + bv; p = p > 0.f ? p : 0.f;
        float di = bf2f(psi[psiIdx(row, 128 + col)]);
        float dj = bf2f(psi[psiIdx(row, 192 + col)]);
        float s  = p * (dj - di);
        atomicAdd(&agg[(size_t)ridx[t * 4 + i] * DD + col], s);
      }
    }
  }
}

// ---------------------------------------------------------------------------
// out = h_d_prev + agg @ Wm  (fp32). 16 rows/block, LDS-staged agg (stride 72
// swizzle: conflict-free broadcast) + float4 Wm reads. Grid 3125.
// ---------------------------------------------------------------------------
__global__ __launch_bounds__(256) void final_out(
    const float* __restrict__ hd,
    const float* __restrict__ agg,
    const float* __restrict__ Wm,   // [64][64] fp32
    float* __restrict__ out)
{
  __shared__ float wmf[DD * DD];    // 16 KB
  __shared__ float arow[16 * 72];   // 4.5 KB, stride-72 swizzle
  int tid = threadIdx.x;
  const float4* wm4 = (const float4*)Wm;
  float4* wf4 = (float4*)wmf;
  #pragma unroll
  for (int i = tid; i < DD * DD / 4; i += 256) wf4[i] = wm4[i];

  int r0 = blockIdx.x * 16;
  {
    float4 av = *(const float4*)(agg + (size_t)r0 * DD + tid * 4);
    int rr = tid >> 4, cc = (tid & 15) * 4;       // tid*4 == rr*64 + cc
    *(float4*)&arow[rr * 72 + cc] = av;
  }
  __syncthreads();

  int row = tid >> 4;
  int cq  = (tid & 15) * 4;
  f32x4 acc = (f32x4){0, 0, 0, 0};
  #pragma unroll
  for (int k = 0; k < DD; ++k) {
    float a = arow[row * 72 + k];
    f32x4 w = *(const f32x4*)&wmf[k * DD + cq];
    acc += a * w;
  }
  size_t o = ((size_t)(r0 + row)) * DD + cq;
  f32x4 h = *(const f32x4*)(hd + o);
  *(f32x4*)(out + o) = h + acc;
}

// ---------------------------------------------------------------------------
extern "C" void kernel_launch(void* const* d_in, const int* in_sizes, int n_in,
                              void* d_out, int out_size, void* d_ws, size_t ws_size,
                              hipStream_t stream) {
  const float* hd = (const float*)d_in[0];
  const float* hs = (const float*)d_in[1];
  const float* ef = (const float*)d_in[2];
  const int* snd  = (const int*)d_in[3];
  const int* rcv  = (const int*)d_in[4];
  const float* W0 = (const float*)d_in[5];
  const float* b0 = (const float*)d_in[6];
  const float* W1 = (const float*)d_in[7];
  const float* b1 = (const float*)d_in[8];
  const float* W2 = (const float*)d_in[9];
  const float* b2 = (const float*)d_in[10];
  const float* Wm = (const float*)d_in[11];
  float* out      = (float*)d_out;

  char* ws = (char*)d_ws;
  float* agg = (float*)ws;                                   // 12,800,000 B
  unsigned short* WT0 = (unsigned short*)(ws + 12800000);    // 81,920 B
  unsigned short* WT1 = WT0 + KIN * HH;                      // 32,768 B
  unsigned short* WT2 = WT1 + HH * HH;                       // 16,384 B
  unsigned short* hdb = WT2 + HH * DD;                       // 6,400,000 B
  unsigned short* hsb = hdb + (size_t)NN * DD;               // 6,400,000 B
                                                             // total ~25.8 MB
  hipMemsetAsync(agg, 0, (size_t)NN * DD * sizeof(float), stream);
  prep_weights<<<256, 256, 0, stream>>>(W0, W1, W2, WT0, WT1, WT2);
  prep_tables<<<NN * DD * 2 / 8 / 256, 256, 0, stream>>>(hd, hs, hdb, hsb);
  edge_mlp<<<EE / TILE_E, 512, 0, stream>>>(hdb, hsb, ef, snd, rcv,
                                            WT0, b0, WT1, b1, WT2, b2, agg);
  final_out<<<NN / 16, 256, 0, stream>>>(hd, agg, Wm, out);
}